// Round 1
// baseline (18148.576 us; speedup 1.0000x reference)
//
#include <hip/hip_runtime.h>

#define NN 100000
#define DD 128
#define RR 4
#define EE 150000
#define HH 8
#define DK 16

// ---- ordered-uint encoding for float atomic max (memset-0 = identity) ----
__device__ __forceinline__ unsigned f2ord(float f) {
    unsigned u = __float_as_uint(f);
    return (u & 0x80000000u) ? ~u : (u | 0x80000000u);
}
__device__ __forceinline__ float ord2f(unsigned u) {
    return (u & 0x80000000u) ? __uint_as_float(u & 0x7fffffffu) : __uint_as_float(~u);
}

// out[m,n] = ((sum_d in_scale*X[m,d]*W[n,d]) + b[n]) * alpha + xres[m,n]*(1-alpha)
// block = 128 threads, lane n owns W row n in registers; 16 rows of X per block
// staged in LDS, read back as uniform-address b128 broadcasts (conflict-free).
__global__ __launch_bounds__(128) void gemm_xwt(
    const float* __restrict__ X,
    const float* __restrict__ W0, const float* __restrict__ W1, const float* __restrict__ W2,
    const float* __restrict__ b0, const float* __restrict__ b1, const float* __restrict__ b2,
    float* __restrict__ outb, float in_scale,
    const float* __restrict__ skip, const float* __restrict__ xres)
{
    const int tid = threadIdx.x;
    const int n = tid;                       // output column
    const long m0 = (long)blockIdx.x * 16;
    const int mat = blockIdx.y;
    const float* W    = (mat == 0) ? W0 : (mat == 1) ? W1 : W2;
    const float* bias = (mat == 0) ? b0 : (mat == 1) ? b1 : b2;
    float* out = outb + (long)mat * NN * DD;

    // W row n -> 32 float4 regs (64KB of W stays hot in L2 across blocks)
    float4 wreg[32];
    const float4* Wr = (const float4*)(W + n * DD);
    #pragma unroll
    for (int j = 0; j < 32; ++j) wreg[j] = Wr[j];

    __shared__ float xs[16 * DD];
    const float4* Xg = (const float4*)(X + m0 * DD);
    #pragma unroll
    for (int j = 0; j < 4; ++j) {
        int p = tid + 128 * j;               // float4 slot within 16x128 tile
        float4 v = Xg[p];
        v.x *= in_scale; v.y *= in_scale; v.z *= in_scale; v.w *= in_scale;
        ((float4*)xs)[p] = v;
    }
    __syncthreads();

    float acc[16];
    #pragma unroll
    for (int mi = 0; mi < 16; ++mi) acc[mi] = 0.f;

    #pragma unroll
    for (int d4 = 0; d4 < 32; ++d4) {
        float4 w = wreg[d4];
        #pragma unroll
        for (int mi = 0; mi < 16; ++mi) {
            float4 xv = ((const float4*)xs)[mi * 32 + d4];   // broadcast read
            acc[mi] = __builtin_fmaf(xv.x, w.x, acc[mi]);
            acc[mi] = __builtin_fmaf(xv.y, w.y, acc[mi]);
            acc[mi] = __builtin_fmaf(xv.z, w.z, acc[mi]);
            acc[mi] = __builtin_fmaf(xv.w, w.w, acc[mi]);
        }
    }

    float al = 1.f, bt = 0.f;
    if (skip) { float s = 1.f / (1.f + __expf(-skip[0])); al = s; bt = 1.f - s; }
    float b = bias[n];
    #pragma unroll
    for (int mi = 0; mi < 16; ++mi) {
        long o = (m0 + mi) * DD + n;
        float r = (acc[mi] + b) * al;
        if (xres) r = __builtin_fmaf(xres[o], bt, r);
        out[o] = r;
    }
}

// one thread per (r,e,h), h fastest -> 8 lanes cover one edge's 512B k/q rows
__global__ __launch_bounds__(256) void edge_att(
    const float* __restrict__ k, const float* __restrict__ q,
    const int* __restrict__ esrc, const int* __restrict__ edst,
    const float* __restrict__ rel_att, const float* __restrict__ rel_pri,
    float* __restrict__ att, unsigned* __restrict__ menc)
{
    int idx = blockIdx.x * 256 + threadIdx.x;     // < R*E*H (exact grid)
    int h = idx & (HH - 1);
    int re = idx >> 3;                            // r*E + e
    int r = re / EE;
    int src = esrc[re], dst = edst[re];

    float kh[16], qh[16];
    const float4* kp = (const float4*)(k + (long)src * DD + h * DK);
    const float4* qp = (const float4*)(q + (long)dst * DD + h * DK);
    #pragma unroll
    for (int i = 0; i < 4; ++i) {
        float4 a = kp[i]; kh[4*i]=a.x; kh[4*i+1]=a.y; kh[4*i+2]=a.z; kh[4*i+3]=a.w;
        float4 b = qp[i]; qh[4*i]=b.x; qh[4*i+1]=b.y; qh[4*i+2]=b.z; qh[4*i+3]=b.w;
    }
    const float* A = rel_att + (((long)r * HH + h) << 8);  // [16][16]
    float key[16];
    #pragma unroll
    for (int f = 0; f < 16; ++f) key[f] = 0.f;
    #pragma unroll
    for (int d = 0; d < 16; ++d) {
        float kd = kh[d];
        const float4* Ar = (const float4*)(A + d * 16);
        #pragma unroll
        for (int f4 = 0; f4 < 4; ++f4) {
            float4 a = Ar[f4];
            key[4*f4]   = __builtin_fmaf(kd, a.x, key[4*f4]);
            key[4*f4+1] = __builtin_fmaf(kd, a.y, key[4*f4+1]);
            key[4*f4+2] = __builtin_fmaf(kd, a.z, key[4*f4+2]);
            key[4*f4+3] = __builtin_fmaf(kd, a.w, key[4*f4+3]);
        }
    }
    float s = 0.f;
    #pragma unroll
    for (int f = 0; f < 16; ++f) s = __builtin_fmaf(qh[f], key[f], s);
    s *= rel_pri[r * HH + h] * 0.25f;             // * rel_pri / sqrt(16)
    att[idx] = s;
    atomicMax(&menc[((long)r * NN + dst) * HH + h], f2ord(s));
}

__global__ __launch_bounds__(256) void edge_exp(
    const int* __restrict__ edst,
    const unsigned* __restrict__ menc,
    float* __restrict__ att, float* __restrict__ ssum)
{
    int idx = blockIdx.x * 256 + threadIdx.x;
    int h = idx & (HH - 1);
    int re = idx >> 3;
    int r = re / EE;
    int dst = edst[re];
    int seg = (r * NN + dst) * HH + h;
    float m = ord2f(menc[seg]);
    float a = __expf(att[idx] - m);
    att[idx] = a;
    atomicAdd(&ssum[seg], a);
}

__global__ __launch_bounds__(256) void edge_scatter(
    const float* __restrict__ v,
    const int* __restrict__ esrc, const int* __restrict__ edst,
    const float* __restrict__ rel_msg,
    const float* __restrict__ att, const float* __restrict__ ssum,
    float* __restrict__ t)
{
    int idx = blockIdx.x * 256 + threadIdx.x;
    int h = idx & (HH - 1);
    int re = idx >> 3;
    int r = re / EE;
    int src = esrc[re], dst = edst[re];
    int seg = (r * NN + dst) * HH + h;
    float w = att[idx] / ssum[seg];

    float vh[16];
    const float4* vp = (const float4*)(v + (long)src * DD + h * DK);
    #pragma unroll
    for (int i = 0; i < 4; ++i) {
        float4 a = vp[i]; vh[4*i]=a.x; vh[4*i+1]=a.y; vh[4*i+2]=a.z; vh[4*i+3]=a.w;
    }
    const float* M = rel_msg + (((long)r * HH + h) << 8);
    float msg[16];
    #pragma unroll
    for (int f = 0; f < 16; ++f) msg[f] = 0.f;
    #pragma unroll
    for (int d = 0; d < 16; ++d) {
        float vd = vh[d];
        const float4* Mr = (const float4*)(M + d * 16);
        #pragma unroll
        for (int f4 = 0; f4 < 4; ++f4) {
            float4 a = Mr[f4];
            msg[4*f4]   = __builtin_fmaf(vd, a.x, msg[4*f4]);
            msg[4*f4+1] = __builtin_fmaf(vd, a.y, msg[4*f4+1]);
            msg[4*f4+2] = __builtin_fmaf(vd, a.z, msg[4*f4+2]);
            msg[4*f4+3] = __builtin_fmaf(vd, a.w, msg[4*f4+3]);
        }
    }
    float* tb = t + (long)dst * DD + h * DK;
    #pragma unroll
    for (int f = 0; f < 16; ++f) atomicAdd(&tb[f], w * msg[f]);
}

extern "C" void kernel_launch(void* const* d_in, const int* in_sizes, int n_in,
                              void* d_out, int out_size, void* d_ws, size_t ws_size,
                              hipStream_t stream)
{
    const float* x   = (const float*)d_in[0];
    const int* esrc  = (const int*)d_in[1];
    const int* edst  = (const int*)d_in[2];
    const float* Wk  = (const float*)d_in[3];
    const float* bk  = (const float*)d_in[4];
    const float* Wq  = (const float*)d_in[5];
    const float* bq  = (const float*)d_in[6];
    const float* Wv  = (const float*)d_in[7];
    const float* bv  = (const float*)d_in[8];
    const float* Wa  = (const float*)d_in[9];
    const float* ba  = (const float*)d_in[10];
    const float* rel_att = (const float*)d_in[11];
    const float* rel_msg = (const float*)d_in[12];
    const float* rel_pri = (const float*)d_in[13];
    const float* skip    = (const float*)d_in[14];
    float* out = (float*)d_out;

    // workspace layout (floats):
    // [k:ND][q:ND][v:ND][att:R*E*H][ssum:R*N*H][menc:R*N*H][t:ND]  = 62.4M floats
    float* ws = (float*)d_ws;
    const long ND = (long)NN * DD;
    float* kbuf = ws;
    float* qbuf = ws + ND;
    float* vbuf = ws + 2 * ND;
    float* attb = ws + 3 * ND;
    float* ssum = attb + (long)RR * EE * HH;
    unsigned* menc = (unsigned*)(ssum + (long)RR * NN * HH);
    float* tbuf = (float*)menc + (long)RR * NN * HH;

    // zero ssum + menc + t (contiguous); menc=0 encodes < -inf (max identity)
    hipMemsetAsync(ssum, 0, ((long)RR * NN * HH * 2 + ND) * sizeof(float), stream);

    // k,q,v projections (grid.y selects weight matrix)
    gemm_xwt<<<dim3(NN / 16, 3), 128, 0, stream>>>(
        x, Wk, Wq, Wv, bk, bq, bv, kbuf, 1.f, nullptr, nullptr);

    const int eb = (RR * EE * HH) / 256;   // 18750, exact
    edge_att<<<eb, 256, 0, stream>>>(kbuf, qbuf, esrc, edst, rel_att, rel_pri, attb, menc);
    edge_exp<<<eb, 256, 0, stream>>>(edst, menc, attb, ssum);
    edge_scatter<<<eb, 256, 0, stream>>>(vbuf, esrc, edst, rel_msg, attb, ssum, tbuf);

    // out = (t/R)@Wa.T + ba, skip-gated with x
    gemm_xwt<<<dim3(NN / 16, 1), 128, 0, stream>>>(
        tbuf, Wa, Wa, Wa, ba, ba, ba, out, 0.25f, skip, x);
}

// Round 2
// 5061.987 us; speedup vs baseline: 3.5853x; 3.5853x over previous
//
#include <hip/hip_runtime.h>

#define NN 100000
#define DD 128
#define RR 4
#define EE 150000
#define HH 8
#define DK 16

#define MT 64
#define KC 64
#define XS_STRIDE 68   // MT+4: keeps 16B alignment, stride ≡ 4 mod 32 banks
#define WS_STRIDE 132  // DD+4

// ---- ordered-uint encoding for float atomic max (memset-0 = identity) ----
__device__ __forceinline__ unsigned f2ord(float f) {
    unsigned u = __float_as_uint(f);
    return (u & 0x80000000u) ? ~u : (u | 0x80000000u);
}
__device__ __forceinline__ float ord2f(unsigned u) {
    return (u & 0x80000000u) ? __uint_as_float(u & 0x7fffffffu) : __uint_as_float(~u);
}

// out[m,n] = ((sum_d in_scale*X[m,d]*W[n,d]) + b[n]) * alpha + xres[m,n]*(1-alpha)
// 256 threads, 64x128 tile, K chunked by 64. X and W staged TRANSPOSED in LDS:
// inner loop per d = 3x ds_read_b128 -> 32 FMAs into acc[4][8] (32 VGPRs, no spill).
__global__ __launch_bounds__(256) void gemm_xwt(
    const float* __restrict__ X,
    const float* __restrict__ W0, const float* __restrict__ W1, const float* __restrict__ W2,
    const float* __restrict__ b0, const float* __restrict__ b1, const float* __restrict__ b2,
    float* __restrict__ outb, float in_scale,
    const float* __restrict__ skip, const float* __restrict__ xres)
{
    const int tid = threadIdx.x;
    const int cg = tid & 15;          // cols cg*8 .. cg*8+7
    const int rg = tid >> 4;          // rows rg*4 .. rg*4+3 (0..15)
    const long m0 = (long)blockIdx.x * MT;
    const int mat = blockIdx.y;
    const float* W    = (mat == 0) ? W0 : (mat == 1) ? W1 : W2;
    const float* bias = (mat == 0) ? b0 : (mat == 1) ? b1 : b2;
    float* out = outb + (long)mat * NN * DD;

    __shared__ float Xs[KC][XS_STRIDE];   // [d][m]
    __shared__ float Ws[KC][WS_STRIDE];   // [d][n]

    float acc[4][8];
    #pragma unroll
    for (int i = 0; i < 4; ++i)
        #pragma unroll
        for (int j = 0; j < 8; ++j) acc[i][j] = 0.f;

    for (int kc = 0; kc < DD; kc += KC) {
        __syncthreads();                   // protect previous chunk
        // stage X chunk: 64 rows x 64 cols -> Xs[d][m]
        #pragma unroll
        for (int i = 0; i < 4; ++i) {
            int f = tid + 256 * i;
            int row = f >> 4, c4 = f & 15;
            long m = m0 + row;
            float4 v = make_float4(0.f, 0.f, 0.f, 0.f);
            if (m < NN) v = ((const float4*)(X + m * DD + kc))[c4];
            Xs[c4*4+0][row] = v.x * in_scale;
            Xs[c4*4+1][row] = v.y * in_scale;
            Xs[c4*4+2][row] = v.z * in_scale;
            Xs[c4*4+3][row] = v.w * in_scale;
        }
        // stage W chunk: 128 rows x 64 cols -> Ws[d][n]
        #pragma unroll
        for (int i = 0; i < 8; ++i) {
            int f = tid + 256 * i;
            int n = f >> 4, c4 = f & 15;
            float4 v = ((const float4*)(W + n * DD + kc))[c4];
            Ws[c4*4+0][n] = v.x;
            Ws[c4*4+1][n] = v.y;
            Ws[c4*4+2][n] = v.z;
            Ws[c4*4+3][n] = v.w;
        }
        __syncthreads();
        #pragma unroll 16
        for (int d = 0; d < KC; ++d) {
            float4 xf = *(const float4*)&Xs[d][rg * 4];       // broadcast among 16 lanes
            float4 wa = *(const float4*)&Ws[d][cg * 8];
            float4 wb = *(const float4*)&Ws[d][cg * 8 + 4];
            float xv[4] = {xf.x, xf.y, xf.z, xf.w};
            float wv[8] = {wa.x, wa.y, wa.z, wa.w, wb.x, wb.y, wb.z, wb.w};
            #pragma unroll
            for (int i = 0; i < 4; ++i)
                #pragma unroll
                for (int j = 0; j < 8; ++j)
                    acc[i][j] = __builtin_fmaf(xv[i], wv[j], acc[i][j]);
        }
    }

    float al = 1.f, bt = 0.f;
    if (skip) { float s = 1.f / (1.f + __expf(-skip[0])); al = s; bt = 1.f - s; }
    const float4* bp = (const float4*)(bias + cg * 8);
    float4 bja = bp[0], bjb = bp[1];

    #pragma unroll
    for (int i = 0; i < 4; ++i) {
        long m = m0 + rg * 4 + i;
        if (m < NN) {
            long o = m * DD + cg * 8;
            float4 ra, rb;
            ra.x = (acc[i][0] + bja.x) * al;
            ra.y = (acc[i][1] + bja.y) * al;
            ra.z = (acc[i][2] + bja.z) * al;
            ra.w = (acc[i][3] + bja.w) * al;
            rb.x = (acc[i][4] + bjb.x) * al;
            rb.y = (acc[i][5] + bjb.y) * al;
            rb.z = (acc[i][6] + bjb.z) * al;
            rb.w = (acc[i][7] + bjb.w) * al;
            if (xres) {
                float4 xa = *(const float4*)(xres + o);
                float4 xb = *(const float4*)(xres + o + 4);
                ra.x = __builtin_fmaf(xa.x, bt, ra.x);
                ra.y = __builtin_fmaf(xa.y, bt, ra.y);
                ra.z = __builtin_fmaf(xa.z, bt, ra.z);
                ra.w = __builtin_fmaf(xa.w, bt, ra.w);
                rb.x = __builtin_fmaf(xb.x, bt, rb.x);
                rb.y = __builtin_fmaf(xb.y, bt, rb.y);
                rb.z = __builtin_fmaf(xb.z, bt, rb.z);
                rb.w = __builtin_fmaf(xb.w, bt, rb.w);
            }
            *(float4*)(out + o) = ra;
            *(float4*)(out + o + 4) = rb;
        }
    }
}

// one thread per (r,e,h), h fastest -> 8 lanes cover one edge's 512B k/q rows
__global__ __launch_bounds__(256) void edge_att(
    const float* __restrict__ k, const float* __restrict__ q,
    const int* __restrict__ esrc, const int* __restrict__ edst,
    const float* __restrict__ rel_att, const float* __restrict__ rel_pri,
    float* __restrict__ att, unsigned* __restrict__ menc)
{
    int idx = blockIdx.x * 256 + threadIdx.x;     // < R*E*H (exact grid)
    int h = idx & (HH - 1);
    int re = idx >> 3;                            // r*E + e
    int r = re / EE;
    int src = esrc[re], dst = edst[re];

    float kh[16], qh[16];
    const float4* kp = (const float4*)(k + (long)src * DD + h * DK);
    const float4* qp = (const float4*)(q + (long)dst * DD + h * DK);
    #pragma unroll
    for (int i = 0; i < 4; ++i) {
        float4 a = kp[i]; kh[4*i]=a.x; kh[4*i+1]=a.y; kh[4*i+2]=a.z; kh[4*i+3]=a.w;
        float4 b = qp[i]; qh[4*i]=b.x; qh[4*i+1]=b.y; qh[4*i+2]=b.z; qh[4*i+3]=b.w;
    }
    const float* A = rel_att + (((long)r * HH + h) << 8);  // [16][16]
    float key[16];
    #pragma unroll
    for (int f = 0; f < 16; ++f) key[f] = 0.f;
    #pragma unroll
    for (int d = 0; d < 16; ++d) {
        float kd = kh[d];
        const float4* Ar = (const float4*)(A + d * 16);
        #pragma unroll
        for (int f4 = 0; f4 < 4; ++f4) {
            float4 a = Ar[f4];
            key[4*f4]   = __builtin_fmaf(kd, a.x, key[4*f4]);
            key[4*f4+1] = __builtin_fmaf(kd, a.y, key[4*f4+1]);
            key[4*f4+2] = __builtin_fmaf(kd, a.z, key[4*f4+2]);
            key[4*f4+3] = __builtin_fmaf(kd, a.w, key[4*f4+3]);
        }
    }
    float s = 0.f;
    #pragma unroll
    for (int f = 0; f < 16; ++f) s = __builtin_fmaf(qh[f], key[f], s);
    s *= rel_pri[r * HH + h] * 0.25f;             // * rel_pri / sqrt(16)
    att[idx] = s;
    atomicMax(&menc[((long)r * NN + dst) * HH + h], f2ord(s));
}

__global__ __launch_bounds__(256) void edge_exp(
    const int* __restrict__ edst,
    const unsigned* __restrict__ menc,
    float* __restrict__ att, float* __restrict__ ssum)
{
    int idx = blockIdx.x * 256 + threadIdx.x;
    int h = idx & (HH - 1);
    int re = idx >> 3;
    int r = re / EE;
    int dst = edst[re];
    int seg = (r * NN + dst) * HH + h;
    float m = ord2f(menc[seg]);
    float a = __expf(att[idx] - m);
    att[idx] = a;
    atomicAdd(&ssum[seg], a);
}

__global__ __launch_bounds__(256) void edge_scatter(
    const float* __restrict__ v,
    const int* __restrict__ esrc, const int* __restrict__ edst,
    const float* __restrict__ rel_msg,
    const float* __restrict__ att, const float* __restrict__ ssum,
    float* __restrict__ t)
{
    int idx = blockIdx.x * 256 + threadIdx.x;
    int h = idx & (HH - 1);
    int re = idx >> 3;
    int r = re / EE;
    int src = esrc[re], dst = edst[re];
    int seg = (r * NN + dst) * HH + h;
    float w = att[idx] / ssum[seg];

    float vh[16];
    const float4* vp = (const float4*)(v + (long)src * DD + h * DK);
    #pragma unroll
    for (int i = 0; i < 4; ++i) {
        float4 a = vp[i]; vh[4*i]=a.x; vh[4*i+1]=a.y; vh[4*i+2]=a.z; vh[4*i+3]=a.w;
    }
    const float* M = rel_msg + (((long)r * HH + h) << 8);
    float msg[16];
    #pragma unroll
    for (int f = 0; f < 16; ++f) msg[f] = 0.f;
    #pragma unroll
    for (int d = 0; d < 16; ++d) {
        float vd = vh[d];
        const float4* Mr = (const float4*)(M + d * 16);
        #pragma unroll
        for (int f4 = 0; f4 < 4; ++f4) {
            float4 a = Mr[f4];
            msg[4*f4]   = __builtin_fmaf(vd, a.x, msg[4*f4]);
            msg[4*f4+1] = __builtin_fmaf(vd, a.y, msg[4*f4+1]);
            msg[4*f4+2] = __builtin_fmaf(vd, a.z, msg[4*f4+2]);
            msg[4*f4+3] = __builtin_fmaf(vd, a.w, msg[4*f4+3]);
        }
    }
    float* tb = t + (long)dst * DD + h * DK;
    #pragma unroll
    for (int f = 0; f < 16; ++f) atomicAdd(&tb[f], w * msg[f]);
}

extern "C" void kernel_launch(void* const* d_in, const int* in_sizes, int n_in,
                              void* d_out, int out_size, void* d_ws, size_t ws_size,
                              hipStream_t stream)
{
    const float* x   = (const float*)d_in[0];
    const int* esrc  = (const int*)d_in[1];
    const int* edst  = (const int*)d_in[2];
    const float* Wk  = (const float*)d_in[3];
    const float* bk  = (const float*)d_in[4];
    const float* Wq  = (const float*)d_in[5];
    const float* bq  = (const float*)d_in[6];
    const float* Wv  = (const float*)d_in[7];
    const float* bv  = (const float*)d_in[8];
    const float* Wa  = (const float*)d_in[9];
    const float* ba  = (const float*)d_in[10];
    const float* rel_att = (const float*)d_in[11];
    const float* rel_msg = (const float*)d_in[12];
    const float* rel_pri = (const float*)d_in[13];
    const float* skip    = (const float*)d_in[14];
    float* out = (float*)d_out;

    // workspace layout (floats):
    // [k:ND][q:ND][v:ND][att:R*E*H][ssum:R*N*H][menc:R*N*H][t:ND]
    float* ws = (float*)d_ws;
    const long ND = (long)NN * DD;
    float* kbuf = ws;
    float* qbuf = ws + ND;
    float* vbuf = ws + 2 * ND;
    float* attb = ws + 3 * ND;
    float* ssum = attb + (long)RR * EE * HH;
    unsigned* menc = (unsigned*)(ssum + (long)RR * NN * HH);
    float* tbuf = (float*)menc + (long)RR * NN * HH;

    // zero ssum + menc + t (contiguous); menc=0 encodes < -inf (max identity)
    hipMemsetAsync(ssum, 0, ((long)RR * NN * HH * 2 + ND) * sizeof(float), stream);

    const int gb = (NN + MT - 1) / MT;   // 1563
    // k,q,v projections (grid.y selects weight matrix)
    gemm_xwt<<<dim3(gb, 3), 256, 0, stream>>>(
        x, Wk, Wq, Wv, bk, bq, bv, kbuf, 1.f, nullptr, nullptr);

    const int eb = (RR * EE * HH) / 256;   // 18750, exact
    edge_att<<<eb, 256, 0, stream>>>(kbuf, qbuf, esrc, edst, rel_att, rel_pri, attb, menc);
    edge_exp<<<eb, 256, 0, stream>>>(edst, menc, attb, ssum);
    edge_scatter<<<eb, 256, 0, stream>>>(vbuf, esrc, edst, rel_msg, attb, ssum, tbuf);

    // out = (t/R)@Wa.T + ba, skip-gated with x
    gemm_xwt<<<dim3(gb, 1), 256, 0, stream>>>(
        tbuf, Wa, Wa, Wa, ba, ba, ba, out, 0.25f, skip, x);
}

// Round 3
// 740.457 us; speedup vs baseline: 24.5100x; 6.8363x over previous
//
#include <hip/hip_runtime.h>

#define NN 100000
#define DD 128
#define RR 4
#define EE 150000
#define HH 8
#define DK 16

#define MT 64
#define KC 64
#define XS_STRIDE 68   // MT+4: keeps 16B alignment, stride ≡ 4 mod 32 banks
#define WS_STRIDE 132  // DD+4

#define NSEG (RR * NN)        // 400000
#define NEDGE (RR * EE)       // 600000
#define SCAN_BLK 256
#define SCAN_ELEMS 1024       // per block (4/thread)
#define SCAN_NB ((NSEG + SCAN_ELEMS - 1) / SCAN_ELEMS)   // 391
#define MAT_STRIDE 264        // 256 + 8 pad: h*264 % 32 spreads banks, 16B aligned

// out[m,n] = ((sum_d in_scale*X[m,d]*W[n,d]) + b[n]) * alpha + xres[m,n]*(1-alpha)
// 256 threads, 64x128 tile, K chunked by 64. X and W staged TRANSPOSED in LDS.
__global__ __launch_bounds__(256) void gemm_xwt(
    const float* __restrict__ X,
    const float* __restrict__ W0, const float* __restrict__ W1, const float* __restrict__ W2,
    const float* __restrict__ b0, const float* __restrict__ b1, const float* __restrict__ b2,
    float* __restrict__ outb, float in_scale,
    const float* __restrict__ skip, const float* __restrict__ xres)
{
    const int tid = threadIdx.x;
    const int cg = tid & 15;          // cols cg*8 .. cg*8+7
    const int rg = tid >> 4;          // rows rg*4 .. rg*4+3
    const long m0 = (long)blockIdx.x * MT;
    const int mat = blockIdx.y;
    const float* W    = (mat == 0) ? W0 : (mat == 1) ? W1 : W2;
    const float* bias = (mat == 0) ? b0 : (mat == 1) ? b1 : b2;
    float* out = outb + (long)mat * NN * DD;

    __shared__ float Xs[KC][XS_STRIDE];   // [d][m]
    __shared__ float Ws[KC][WS_STRIDE];   // [d][n]

    float acc[4][8];
    #pragma unroll
    for (int i = 0; i < 4; ++i)
        #pragma unroll
        for (int j = 0; j < 8; ++j) acc[i][j] = 0.f;

    for (int kc = 0; kc < DD; kc += KC) {
        __syncthreads();
        #pragma unroll
        for (int i = 0; i < 4; ++i) {
            int f = tid + 256 * i;
            int row = f >> 4, c4 = f & 15;
            long m = m0 + row;
            float4 v = make_float4(0.f, 0.f, 0.f, 0.f);
            if (m < NN) v = ((const float4*)(X + m * DD + kc))[c4];
            Xs[c4*4+0][row] = v.x * in_scale;
            Xs[c4*4+1][row] = v.y * in_scale;
            Xs[c4*4+2][row] = v.z * in_scale;
            Xs[c4*4+3][row] = v.w * in_scale;
        }
        #pragma unroll
        for (int i = 0; i < 8; ++i) {
            int f = tid + 256 * i;
            int n = f >> 4, c4 = f & 15;
            float4 v = ((const float4*)(W + n * DD + kc))[c4];
            Ws[c4*4+0][n] = v.x;
            Ws[c4*4+1][n] = v.y;
            Ws[c4*4+2][n] = v.z;
            Ws[c4*4+3][n] = v.w;
        }
        __syncthreads();
        #pragma unroll 16
        for (int d = 0; d < KC; ++d) {
            float4 xf = *(const float4*)&Xs[d][rg * 4];
            float4 wa = *(const float4*)&Ws[d][cg * 8];
            float4 wb = *(const float4*)&Ws[d][cg * 8 + 4];
            float xv[4] = {xf.x, xf.y, xf.z, xf.w};
            float wv[8] = {wa.x, wa.y, wa.z, wa.w, wb.x, wb.y, wb.z, wb.w};
            #pragma unroll
            for (int i = 0; i < 4; ++i)
                #pragma unroll
                for (int j = 0; j < 8; ++j)
                    acc[i][j] = __builtin_fmaf(xv[i], wv[j], acc[i][j]);
        }
    }

    float al = 1.f, bt = 0.f;
    if (skip) { float s = 1.f / (1.f + __expf(-skip[0])); al = s; bt = 1.f - s; }
    const float4* bp = (const float4*)(bias + cg * 8);
    float4 bja = bp[0], bjb = bp[1];

    #pragma unroll
    for (int i = 0; i < 4; ++i) {
        long m = m0 + rg * 4 + i;
        if (m < NN) {
            long o = m * DD + cg * 8;
            float4 ra, rb;
            ra.x = (acc[i][0] + bja.x) * al;
            ra.y = (acc[i][1] + bja.y) * al;
            ra.z = (acc[i][2] + bja.z) * al;
            ra.w = (acc[i][3] + bja.w) * al;
            rb.x = (acc[i][4] + bjb.x) * al;
            rb.y = (acc[i][5] + bjb.y) * al;
            rb.z = (acc[i][6] + bjb.z) * al;
            rb.w = (acc[i][7] + bjb.w) * al;
            if (xres) {
                float4 xa = *(const float4*)(xres + o);
                float4 xb = *(const float4*)(xres + o + 4);
                ra.x = __builtin_fmaf(xa.x, bt, ra.x);
                ra.y = __builtin_fmaf(xa.y, bt, ra.y);
                ra.z = __builtin_fmaf(xa.z, bt, ra.z);
                ra.w = __builtin_fmaf(xa.w, bt, ra.w);
                rb.x = __builtin_fmaf(xb.x, bt, rb.x);
                rb.y = __builtin_fmaf(xb.y, bt, rb.y);
                rb.z = __builtin_fmaf(xb.z, bt, rb.z);
                rb.w = __builtin_fmaf(xb.w, bt, rb.w);
            }
            *(float4*)(out + o) = ra;
            *(float4*)(out + o + 4) = rb;
        }
    }
}

// ---------- CSR build: histogram -> scan -> fill ----------

__global__ __launch_bounds__(256) void csr_hist(
    const int* __restrict__ edst, int* __restrict__ cnt)
{
    int idx = blockIdx.x * 256 + threadIdx.x;
    if (idx >= NEDGE) return;
    int r = idx / EE;
    atomicAdd(&cnt[r * NN + edst[idx]], 1);
}

__global__ __launch_bounds__(SCAN_BLK) void scan1(
    const int* __restrict__ cnt, int* __restrict__ offs, int* __restrict__ bsum)
{
    __shared__ int sh[SCAN_BLK];
    int blk = blockIdx.x, tid = threadIdx.x;
    int base = blk * SCAN_ELEMS + tid * 4;
    int v0 = 0, v1 = 0, v2 = 0, v3 = 0;
    if (base + 3 < NSEG) {
        int4 t = *(const int4*)(cnt + base);
        v0 = t.x; v1 = t.y; v2 = t.z; v3 = t.w;
    } else {
        if (base + 0 < NSEG) v0 = cnt[base + 0];
        if (base + 1 < NSEG) v1 = cnt[base + 1];
        if (base + 2 < NSEG) v2 = cnt[base + 2];
        if (base + 3 < NSEG) v3 = cnt[base + 3];
    }
    int tsum = v0 + v1 + v2 + v3;
    sh[tid] = tsum;
    __syncthreads();
    #pragma unroll
    for (int d = 1; d < SCAN_BLK; d <<= 1) {
        int x = (tid >= d) ? sh[tid - d] : 0;
        __syncthreads();
        sh[tid] += x;
        __syncthreads();
    }
    int excl = sh[tid] - tsum;
    int r0 = excl, r1 = r0 + v0, r2 = r1 + v1, r3 = r2 + v2;
    if (base + 3 < NSEG) {
        *(int4*)(offs + base) = make_int4(r0, r1, r2, r3);
    } else {
        if (base + 0 < NSEG) offs[base + 0] = r0;
        if (base + 1 < NSEG) offs[base + 1] = r1;
        if (base + 2 < NSEG) offs[base + 2] = r2;
        if (base + 3 < NSEG) offs[base + 3] = r3;
    }
    if (tid == SCAN_BLK - 1) bsum[blk] = sh[tid];
}

__global__ __launch_bounds__(512) void scan2(int* __restrict__ bsum)
{
    __shared__ int sh[512];
    int tid = threadIdx.x;
    int v = (tid < SCAN_NB) ? bsum[tid] : 0;
    sh[tid] = v;
    __syncthreads();
    #pragma unroll
    for (int d = 1; d < 512; d <<= 1) {
        int x = (tid >= d) ? sh[tid - d] : 0;
        __syncthreads();
        sh[tid] += x;
        __syncthreads();
    }
    if (tid < SCAN_NB) bsum[tid] = sh[tid] - v;   // exclusive, in place
}

__global__ __launch_bounds__(SCAN_BLK) void scan3(
    int* __restrict__ offs, const int* __restrict__ bsum)
{
    int blk = blockIdx.x;
    int add = bsum[blk];
    if (add == 0) return;
    int base = blk * SCAN_ELEMS + threadIdx.x * 4;
    #pragma unroll
    for (int j = 0; j < 4; ++j)
        if (base + j < NSEG) offs[base + j] += add;
}

// fill: atomicAdd on offs itself; afterwards offs[seg] == segment end,
// so gather uses beg = seg ? offs[seg-1] : 0, end = offs[seg].
__global__ __launch_bounds__(256) void csr_fill(
    const int* __restrict__ esrc, const int* __restrict__ edst,
    int* __restrict__ offs, int* __restrict__ csr_src)
{
    int idx = blockIdx.x * 256 + threadIdx.x;
    if (idx >= NEDGE) return;
    int r = idx / EE;
    int pos = atomicAdd(&offs[r * NN + edst[idx]], 1);
    csr_src[pos] = esrc[idx];
}

// ---------- fused per-dst gather: att + online softmax + weighted agg ----------
// thread = (dst,h); loops r=0..3. Identities used:
//   att_e = k[src] . (A[r,h] @ q[dst])          (qbar computed once per segment)
//   sum_e attn_e (v[src].M) = (sum_e attn_e v[src]) . M   (matvec once per segment)
#define GT 512
__global__ __launch_bounds__(GT) void gather_agg(
    const float* __restrict__ k, const float* __restrict__ q, const float* __restrict__ v,
    const int* __restrict__ csr_src, const int* __restrict__ offs,
    const float* __restrict__ rel_att, const float* __restrict__ rel_msg,
    const float* __restrict__ rel_pri, float* __restrict__ t)
{
    __shared__ float As[32 * MAT_STRIDE];
    __shared__ float Ms[32 * MAT_STRIDE];
    const int tid = threadIdx.x;
    for (int i = tid; i < 32 * MAT_STRIDE; i += GT) {
        int m = i / MAT_STRIDE, off = i % MAT_STRIDE;
        if (off < 256) {
            As[i] = rel_att[m * 256 + off];
            Ms[i] = rel_msg[m * 256 + off];
        }
    }
    __syncthreads();

    int gidx = blockIdx.x * GT + tid;
    if (gidx >= NN * HH) return;
    const int dst = gidx >> 3, h = gidx & 7;

    float qh[16];
    {
        const float4* qp = (const float4*)(q + (long)dst * DD + h * DK);
        #pragma unroll
        for (int i = 0; i < 4; ++i) {
            float4 a = qp[i];
            qh[4*i] = a.x; qh[4*i+1] = a.y; qh[4*i+2] = a.z; qh[4*i+3] = a.w;
        }
    }

    float tacc[16];
    #pragma unroll
    for (int f = 0; f < 16; ++f) tacc[f] = 0.f;

    for (int r = 0; r < RR; ++r) {
        const float* A = &As[(r * HH + h) * MAT_STRIDE];
        const float* M = &Ms[(r * HH + h) * MAT_STRIDE];
        const float pri = rel_pri[r * HH + h] * 0.25f;   // pri / sqrt(dk)

        // qbar[d] = sum_f A[d][f] * qh[f]
        float qbar[16];
        #pragma unroll
        for (int d = 0; d < 16; ++d) {
            float4 a0 = *(const float4*)(A + d * 16);
            float4 a1 = *(const float4*)(A + d * 16 + 4);
            float4 a2 = *(const float4*)(A + d * 16 + 8);
            float4 a3 = *(const float4*)(A + d * 16 + 12);
            float acc = a0.x * qh[0];
            acc = __builtin_fmaf(a0.y, qh[1], acc);
            acc = __builtin_fmaf(a0.z, qh[2], acc);
            acc = __builtin_fmaf(a0.w, qh[3], acc);
            acc = __builtin_fmaf(a1.x, qh[4], acc);
            acc = __builtin_fmaf(a1.y, qh[5], acc);
            acc = __builtin_fmaf(a1.z, qh[6], acc);
            acc = __builtin_fmaf(a1.w, qh[7], acc);
            acc = __builtin_fmaf(a2.x, qh[8], acc);
            acc = __builtin_fmaf(a2.y, qh[9], acc);
            acc = __builtin_fmaf(a2.z, qh[10], acc);
            acc = __builtin_fmaf(a2.w, qh[11], acc);
            acc = __builtin_fmaf(a3.x, qh[12], acc);
            acc = __builtin_fmaf(a3.y, qh[13], acc);
            acc = __builtin_fmaf(a3.z, qh[14], acc);
            acc = __builtin_fmaf(a3.w, qh[15], acc);
            qbar[d] = acc;
        }

        const int seg = r * NN + dst;
        const int beg = seg ? offs[seg - 1] : 0;
        const int end = offs[seg];

        float mx = -INFINITY, s = 0.f;
        float vb[16];
        #pragma unroll
        for (int f = 0; f < 16; ++f) vb[f] = 0.f;

        for (int e = beg; e < end; ++e) {
            int src = csr_src[e];
            const float4* kp = (const float4*)(k + (long)src * DD + h * DK);
            const float4* vp = (const float4*)(v + (long)src * DD + h * DK);
            float4 k0 = kp[0], k1 = kp[1], k2 = kp[2], k3 = kp[3];
            float att = k0.x * qbar[0];
            att = __builtin_fmaf(k0.y, qbar[1], att);
            att = __builtin_fmaf(k0.z, qbar[2], att);
            att = __builtin_fmaf(k0.w, qbar[3], att);
            att = __builtin_fmaf(k1.x, qbar[4], att);
            att = __builtin_fmaf(k1.y, qbar[5], att);
            att = __builtin_fmaf(k1.z, qbar[6], att);
            att = __builtin_fmaf(k1.w, qbar[7], att);
            att = __builtin_fmaf(k2.x, qbar[8], att);
            att = __builtin_fmaf(k2.y, qbar[9], att);
            att = __builtin_fmaf(k2.z, qbar[10], att);
            att = __builtin_fmaf(k2.w, qbar[11], att);
            att = __builtin_fmaf(k3.x, qbar[12], att);
            att = __builtin_fmaf(k3.y, qbar[13], att);
            att = __builtin_fmaf(k3.z, qbar[14], att);
            att = __builtin_fmaf(k3.w, qbar[15], att);
            att *= pri;

            float nm = fmaxf(mx, att);
            float eo = __expf(mx - nm);     // 0 on first iter (mx = -inf)
            float ea = __expf(att - nm);
            s = s * eo + ea;
            float4 v0 = vp[0], v1 = vp[1], v2 = vp[2], v3 = vp[3];
            vb[0]  = __builtin_fmaf(vb[0],  eo, ea * v0.x);
            vb[1]  = __builtin_fmaf(vb[1],  eo, ea * v0.y);
            vb[2]  = __builtin_fmaf(vb[2],  eo, ea * v0.z);
            vb[3]  = __builtin_fmaf(vb[3],  eo, ea * v0.w);
            vb[4]  = __builtin_fmaf(vb[4],  eo, ea * v1.x);
            vb[5]  = __builtin_fmaf(vb[5],  eo, ea * v1.y);
            vb[6]  = __builtin_fmaf(vb[6],  eo, ea * v1.z);
            vb[7]  = __builtin_fmaf(vb[7],  eo, ea * v1.w);
            vb[8]  = __builtin_fmaf(vb[8],  eo, ea * v2.x);
            vb[9]  = __builtin_fmaf(vb[9],  eo, ea * v2.y);
            vb[10] = __builtin_fmaf(vb[10], eo, ea * v2.z);
            vb[11] = __builtin_fmaf(vb[11], eo, ea * v2.w);
            vb[12] = __builtin_fmaf(vb[12], eo, ea * v3.x);
            vb[13] = __builtin_fmaf(vb[13], eo, ea * v3.y);
            vb[14] = __builtin_fmaf(vb[14], eo, ea * v3.z);
            vb[15] = __builtin_fmaf(vb[15], eo, ea * v3.w);
            mx = nm;
        }

        if (s > 0.f) {
            float inv = 1.f / s;
            // u[f] = sum_d vb[d] * M[d][f]; tacc += u * inv
            float u[16];
            #pragma unroll
            for (int f = 0; f < 16; ++f) u[f] = 0.f;
            #pragma unroll
            for (int d = 0; d < 16; ++d) {
                float vd = vb[d];
                float4 m0 = *(const float4*)(M + d * 16);
                float4 m1 = *(const float4*)(M + d * 16 + 4);
                float4 m2 = *(const float4*)(M + d * 16 + 8);
                float4 m3 = *(const float4*)(M + d * 16 + 12);
                u[0]  = __builtin_fmaf(vd, m0.x, u[0]);
                u[1]  = __builtin_fmaf(vd, m0.y, u[1]);
                u[2]  = __builtin_fmaf(vd, m0.z, u[2]);
                u[3]  = __builtin_fmaf(vd, m0.w, u[3]);
                u[4]  = __builtin_fmaf(vd, m1.x, u[4]);
                u[5]  = __builtin_fmaf(vd, m1.y, u[5]);
                u[6]  = __builtin_fmaf(vd, m1.z, u[6]);
                u[7]  = __builtin_fmaf(vd, m1.w, u[7]);
                u[8]  = __builtin_fmaf(vd, m2.x, u[8]);
                u[9]  = __builtin_fmaf(vd, m2.y, u[9]);
                u[10] = __builtin_fmaf(vd, m2.z, u[10]);
                u[11] = __builtin_fmaf(vd, m2.w, u[11]);
                u[12] = __builtin_fmaf(vd, m3.x, u[12]);
                u[13] = __builtin_fmaf(vd, m3.y, u[13]);
                u[14] = __builtin_fmaf(vd, m3.z, u[14]);
                u[15] = __builtin_fmaf(vd, m3.w, u[15]);
            }
            #pragma unroll
            for (int f = 0; f < 16; ++f)
                tacc[f] = __builtin_fmaf(u[f], inv, tacc[f]);
        }
    }

    float* tp = t + (long)dst * DD + h * DK;
    #pragma unroll
    for (int i = 0; i < 4; ++i) {
        float4 o;
        o.x = tacc[4*i]; o.y = tacc[4*i+1]; o.z = tacc[4*i+2]; o.w = tacc[4*i+3];
        *(float4*)(tp + 4 * i) = o;
    }
}

extern "C" void kernel_launch(void* const* d_in, const int* in_sizes, int n_in,
                              void* d_out, int out_size, void* d_ws, size_t ws_size,
                              hipStream_t stream)
{
    const float* x   = (const float*)d_in[0];
    const int* esrc  = (const int*)d_in[1];
    const int* edst  = (const int*)d_in[2];
    const float* Wk  = (const float*)d_in[3];
    const float* bk  = (const float*)d_in[4];
    const float* Wq  = (const float*)d_in[5];
    const float* bq  = (const float*)d_in[6];
    const float* Wv  = (const float*)d_in[7];
    const float* bv  = (const float*)d_in[8];
    const float* Wa  = (const float*)d_in[9];
    const float* ba  = (const float*)d_in[10];
    const float* rel_att = (const float*)d_in[11];
    const float* rel_msg = (const float*)d_in[12];
    const float* rel_pri = (const float*)d_in[13];
    const float* skip    = (const float*)d_in[14];
    float* out = (float*)d_out;

    // ws layout (floats): [k:ND][q:ND][v:ND][t:ND] then ints: [cnt][offs][bsum:512][csr]
    float* ws = (float*)d_ws;
    const long ND = (long)NN * DD;
    float* kbuf = ws;
    float* qbuf = ws + ND;
    float* vbuf = ws + 2 * ND;
    float* tbuf = ws + 3 * ND;
    int* cnt  = (int*)(ws + 4 * ND);
    int* offs = cnt + NSEG;
    int* bsum = offs + NSEG;
    int* csr  = bsum + 512;

    hipMemsetAsync(cnt, 0, NSEG * sizeof(int), stream);

    const int gb = (NN + MT - 1) / MT;
    gemm_xwt<<<dim3(gb, 3), 256, 0, stream>>>(
        x, Wk, Wq, Wv, bk, bq, bv, kbuf, 1.f, nullptr, nullptr);

    const int ebk = (NEDGE + 255) / 256;
    csr_hist<<<ebk, 256, 0, stream>>>(edst, cnt);
    scan1<<<SCAN_NB, SCAN_BLK, 0, stream>>>(cnt, offs, bsum);
    scan2<<<1, 512, 0, stream>>>(bsum);
    scan3<<<SCAN_NB, SCAN_BLK, 0, stream>>>(offs, bsum);
    csr_fill<<<ebk, 256, 0, stream>>>(esrc, edst, offs, csr);

    gather_agg<<<(NN * HH + GT - 1) / GT, GT, 0, stream>>>(
        kbuf, qbuf, vbuf, csr, offs, rel_att, rel_msg, rel_pri, tbuf);

    // out = (t/R)@Wa.T + ba, skip-gated with x
    gemm_xwt<<<dim3(gb, 1), 256, 0, stream>>>(
        tbuf, Wa, Wa, Wa, ba, ba, ba, out, 0.25f, skip, x);
}

// Round 5
// 504.862 us; speedup vs baseline: 35.9476x; 1.4667x over previous
//
#include <hip/hip_runtime.h>

#define NN 100000
#define DD 128
#define RR 4
#define EE 150000
#define HH 8
#define DK 16

#define MT 64
#define KC 64
#define XS_STRIDE 68   // keeps 16B alignment, stride ≡ 4 mod 32 banks
#define WS_STRIDE 132  // DD+4

#define NSEG (RR * NN)        // 400000
#define NEDGE (RR * EE)       // 600000
#define SCAN_BLK 256
#define SCAN_ELEMS 1024
#define SCAN_NB ((NSEG + SCAN_ELEMS - 1) / SCAN_ELEMS)   // 391
#define MAT_STRIDE 264        // 256+8 pad: h*264%32 spreads banks, 16B aligned

// f32 -> bf16 round-to-nearest-even
__device__ __forceinline__ unsigned short f2bf(float f) {
    unsigned u = __float_as_uint(f);
    return (unsigned short)((u + 0x7fffu + ((u >> 16) & 1u)) >> 16);
}
__device__ __forceinline__ float bflo(unsigned w) { return __uint_as_float(w << 16); }
__device__ __forceinline__ float bfhi(unsigned w) { return __uint_as_float(w & 0xffff0000u); }

// ---------- q/k/v projections (R3-proven barrier structure, grid.y = matrix) ----------
// q (mat 0) written f32; k (mat 1) / v (mat 2) written bf16 packed:
// kv[node][h] = 16 bf16 k | 16 bf16 v  (64 B = one cache line per (node,head)).
__global__ __launch_bounds__(256) void gemm_qkv(
    const float* __restrict__ X,
    const float* __restrict__ Wq, const float* __restrict__ Wk, const float* __restrict__ Wv,
    const float* __restrict__ bq, const float* __restrict__ bk, const float* __restrict__ bv,
    float* __restrict__ qout, unsigned* __restrict__ kv)
{
    const int tid = threadIdx.x;
    const int cg = tid & 15;          // output cols cg*8..+7
    const int rg = tid >> 4;          // output rows rg*4..+3
    const long m0 = (long)blockIdx.x * MT;
    const int mat = blockIdx.y;
    const float* W    = (mat == 0) ? Wq : (mat == 1) ? Wk : Wv;
    const float* bias = (mat == 0) ? bq : (mat == 1) ? bk : bv;

    __shared__ float Xs[KC][XS_STRIDE];   // [d][m]
    __shared__ float Ws[KC][WS_STRIDE];   // [d][n]

    float acc[4][8];
    #pragma unroll
    for (int i = 0; i < 4; ++i)
        #pragma unroll
        for (int j = 0; j < 8; ++j) acc[i][j] = 0.f;

    for (int kc = 0; kc < DD; kc += KC) {
        __syncthreads();                   // protect previous chunk's reads
        #pragma unroll
        for (int i = 0; i < 4; ++i) {
            int f = tid + 256 * i;
            int row = f >> 4, c4 = f & 15;
            long m = m0 + row;
            float4 v = make_float4(0.f, 0.f, 0.f, 0.f);
            if (m < NN) v = ((const float4*)(X + m * DD + kc))[c4];
            Xs[c4*4+0][row] = v.x;
            Xs[c4*4+1][row] = v.y;
            Xs[c4*4+2][row] = v.z;
            Xs[c4*4+3][row] = v.w;
        }
        #pragma unroll
        for (int i = 0; i < 8; ++i) {
            int f = tid + 256 * i;
            int n = f >> 4, c4 = f & 15;
            float4 v = ((const float4*)(W + n * DD + kc))[c4];
            Ws[c4*4+0][n] = v.x;
            Ws[c4*4+1][n] = v.y;
            Ws[c4*4+2][n] = v.z;
            Ws[c4*4+3][n] = v.w;
        }
        __syncthreads();
        #pragma unroll 16
        for (int d = 0; d < KC; ++d) {
            float4 xf = *(const float4*)&Xs[d][rg * 4];
            float4 wa = *(const float4*)&Ws[d][cg * 8];
            float4 wb = *(const float4*)&Ws[d][cg * 8 + 4];
            float xv[4] = {xf.x, xf.y, xf.z, xf.w};
            float wv[8] = {wa.x, wa.y, wa.z, wa.w, wb.x, wb.y, wb.z, wb.w};
            #pragma unroll
            for (int i = 0; i < 4; ++i)
                #pragma unroll
                for (int j = 0; j < 8; ++j)
                    acc[i][j] = __builtin_fmaf(xv[i], wv[j], acc[i][j]);
        }
    }

    const float4* bp = (const float4*)(bias + cg * 8);
    float4 b0 = bp[0], b1 = bp[1];
    float bb[8] = {b0.x, b0.y, b0.z, b0.w, b1.x, b1.y, b1.z, b1.w};

    if (mat == 0) {
        #pragma unroll
        for (int i = 0; i < 4; ++i) {
            long m = m0 + rg * 4 + i;
            if (m < NN) {
                long o = m * DD + cg * 8;
                float4 ra, rb;
                ra.x = acc[i][0] + bb[0]; ra.y = acc[i][1] + bb[1];
                ra.z = acc[i][2] + bb[2]; ra.w = acc[i][3] + bb[3];
                rb.x = acc[i][4] + bb[4]; rb.y = acc[i][5] + bb[5];
                rb.z = acc[i][6] + bb[6]; rb.w = acc[i][7] + bb[7];
                *(float4*)(qout + o) = ra;
                *(float4*)(qout + o + 4) = rb;
            }
        }
    } else {
        const int h = cg >> 1, dh2 = (cg & 1) * 4;   // uint offset within 8-uint half
        const int slot = (mat == 1) ? 0 : 8;         // k at +0 uints, v at +8
        #pragma unroll
        for (int i = 0; i < 4; ++i) {
            long m = m0 + rg * 4 + i;
            if (m < NN) {
                uint4 u;
                u.x = (unsigned)f2bf(acc[i][0] + bb[0]) | ((unsigned)f2bf(acc[i][1] + bb[1]) << 16);
                u.y = (unsigned)f2bf(acc[i][2] + bb[2]) | ((unsigned)f2bf(acc[i][3] + bb[3]) << 16);
                u.z = (unsigned)f2bf(acc[i][4] + bb[4]) | ((unsigned)f2bf(acc[i][5] + bb[5]) << 16);
                u.w = (unsigned)f2bf(acc[i][6] + bb[6]) | ((unsigned)f2bf(acc[i][7] + bb[7]) << 16);
                *(uint4*)(kv + m * 128 + h * 16 + slot + dh2) = u;
            }
        }
    }
}

// ---------- output GEMM (f32, skip-gated residual) ----------
__global__ __launch_bounds__(256) void gemm_out(
    const float* __restrict__ X, const float* __restrict__ W, const float* __restrict__ bias,
    float* __restrict__ out, float in_scale,
    const float* __restrict__ skip, const float* __restrict__ xres)
{
    const int tid = threadIdx.x;
    const int cg = tid & 15;
    const int rg = tid >> 4;
    const long m0 = (long)blockIdx.x * MT;

    __shared__ float Xs[KC][XS_STRIDE];
    __shared__ float Ws[KC][WS_STRIDE];

    float acc[4][8];
    #pragma unroll
    for (int i = 0; i < 4; ++i)
        #pragma unroll
        for (int j = 0; j < 8; ++j) acc[i][j] = 0.f;

    for (int kc = 0; kc < DD; kc += KC) {
        __syncthreads();
        #pragma unroll
        for (int i = 0; i < 4; ++i) {
            int f = tid + 256 * i;
            int row = f >> 4, c4 = f & 15;
            long m = m0 + row;
            float4 v = make_float4(0.f, 0.f, 0.f, 0.f);
            if (m < NN) v = ((const float4*)(X + m * DD + kc))[c4];
            Xs[c4*4+0][row] = v.x * in_scale;
            Xs[c4*4+1][row] = v.y * in_scale;
            Xs[c4*4+2][row] = v.z * in_scale;
            Xs[c4*4+3][row] = v.w * in_scale;
        }
        #pragma unroll
        for (int i = 0; i < 8; ++i) {
            int f = tid + 256 * i;
            int n = f >> 4, c4 = f & 15;
            float4 v = ((const float4*)(W + n * DD + kc))[c4];
            Ws[c4*4+0][n] = v.x;
            Ws[c4*4+1][n] = v.y;
            Ws[c4*4+2][n] = v.z;
            Ws[c4*4+3][n] = v.w;
        }
        __syncthreads();
        #pragma unroll 16
        for (int d = 0; d < KC; ++d) {
            float4 xf = *(const float4*)&Xs[d][rg * 4];
            float4 wa = *(const float4*)&Ws[d][cg * 8];
            float4 wb = *(const float4*)&Ws[d][cg * 8 + 4];
            float xv[4] = {xf.x, xf.y, xf.z, xf.w};
            float wv[8] = {wa.x, wa.y, wa.z, wa.w, wb.x, wb.y, wb.z, wb.w};
            #pragma unroll
            for (int i = 0; i < 4; ++i)
                #pragma unroll
                for (int j = 0; j < 8; ++j)
                    acc[i][j] = __builtin_fmaf(xv[i], wv[j], acc[i][j]);
        }
    }

    float s = 1.f / (1.f + __expf(-skip[0]));
    float al = s, bt = 1.f - s;
    const float4* bp = (const float4*)(bias + cg * 8);
    float4 bja = bp[0], bjb = bp[1];

    #pragma unroll
    for (int i = 0; i < 4; ++i) {
        long m = m0 + rg * 4 + i;
        if (m < NN) {
            long o = m * DD + cg * 8;
            float4 ra, rb;
            ra.x = (acc[i][0] + bja.x) * al;
            ra.y = (acc[i][1] + bja.y) * al;
            ra.z = (acc[i][2] + bja.z) * al;
            ra.w = (acc[i][3] + bja.w) * al;
            rb.x = (acc[i][4] + bjb.x) * al;
            rb.y = (acc[i][5] + bjb.y) * al;
            rb.z = (acc[i][6] + bjb.z) * al;
            rb.w = (acc[i][7] + bjb.w) * al;
            float4 xa = *(const float4*)(xres + o);
            float4 xb = *(const float4*)(xres + o + 4);
            ra.x = __builtin_fmaf(xa.x, bt, ra.x);
            ra.y = __builtin_fmaf(xa.y, bt, ra.y);
            ra.z = __builtin_fmaf(xa.z, bt, ra.z);
            ra.w = __builtin_fmaf(xa.w, bt, ra.w);
            rb.x = __builtin_fmaf(xb.x, bt, rb.x);
            rb.y = __builtin_fmaf(xb.y, bt, rb.y);
            rb.z = __builtin_fmaf(xb.z, bt, rb.z);
            rb.w = __builtin_fmaf(xb.w, bt, rb.w);
            *(float4*)(out + o) = ra;
            *(float4*)(out + o + 4) = rb;
        }
    }
}

// ---------- CSR build: histogram -> scan -> fill ----------
// offs[] is IMMUTABLE after scan (exclusive prefix); csr_fill bumps cur[].

__global__ __launch_bounds__(256) void csr_hist(
    const int* __restrict__ edst, int* __restrict__ cnt)
{
    int idx = blockIdx.x * 256 + threadIdx.x;
    if (idx >= NEDGE) return;
    int r = idx / EE;
    atomicAdd(&cnt[r * NN + edst[idx]], 1);
}

__global__ __launch_bounds__(SCAN_BLK) void scan1(
    const int* __restrict__ cnt, int* __restrict__ offs, int* __restrict__ bsum)
{
    __shared__ int sh[SCAN_BLK];
    int blk = blockIdx.x, tid = threadIdx.x;
    int base = blk * SCAN_ELEMS + tid * 4;
    int v0 = 0, v1 = 0, v2 = 0, v3 = 0;
    if (base + 3 < NSEG) {
        int4 t = *(const int4*)(cnt + base);
        v0 = t.x; v1 = t.y; v2 = t.z; v3 = t.w;
    } else {
        if (base + 0 < NSEG) v0 = cnt[base + 0];
        if (base + 1 < NSEG) v1 = cnt[base + 1];
        if (base + 2 < NSEG) v2 = cnt[base + 2];
        if (base + 3 < NSEG) v3 = cnt[base + 3];
    }
    int tsum = v0 + v1 + v2 + v3;
    sh[tid] = tsum;
    __syncthreads();
    #pragma unroll
    for (int d = 1; d < SCAN_BLK; d <<= 1) {
        int x = (tid >= d) ? sh[tid - d] : 0;
        __syncthreads();
        sh[tid] += x;
        __syncthreads();
    }
    int excl = sh[tid] - tsum;
    int r0 = excl, r1 = r0 + v0, r2 = r1 + v1, r3 = r2 + v2;
    if (base + 3 < NSEG) {
        *(int4*)(offs + base) = make_int4(r0, r1, r2, r3);
    } else {
        if (base + 0 < NSEG) offs[base + 0] = r0;
        if (base + 1 < NSEG) offs[base + 1] = r1;
        if (base + 2 < NSEG) offs[base + 2] = r2;
        if (base + 3 < NSEG) offs[base + 3] = r3;
    }
    if (tid == SCAN_BLK - 1) bsum[blk] = sh[tid];
}

__global__ __launch_bounds__(512) void scan2(int* __restrict__ bsum)
{
    __shared__ int sh[512];
    int tid = threadIdx.x;
    int v = (tid < SCAN_NB) ? bsum[tid] : 0;
    sh[tid] = v;
    __syncthreads();
    #pragma unroll
    for (int d = 1; d < 512; d <<= 1) {
        int x = (tid >= d) ? sh[tid - d] : 0;
        __syncthreads();
        sh[tid] += x;
        __syncthreads();
    }
    if (tid < SCAN_NB) bsum[tid] = sh[tid] - v;   // exclusive block sums
}

__global__ __launch_bounds__(SCAN_BLK) void scan3(
    int* __restrict__ offs, int* __restrict__ cur, const int* __restrict__ bsum)
{
    int blk = blockIdx.x;
    int add = bsum[blk];
    int base = blk * SCAN_ELEMS + threadIdx.x * 4;
    #pragma unroll
    for (int j = 0; j < 4; ++j)
        if (base + j < NSEG) {
            int v = offs[base + j] + add;
            offs[base + j] = v;
            cur[base + j] = v;
        }
}

__global__ __launch_bounds__(256) void csr_fill(
    const int* __restrict__ esrc, const int* __restrict__ edst,
    int* __restrict__ cur, int* __restrict__ csr_src)
{
    int idx = blockIdx.x * 256 + threadIdx.x;
    if (idx >= NEDGE) return;
    int r = idx / EE;
    int pos = atomicAdd(&cur[r * NN + edst[idx]], 1);
    csr_src[pos] = esrc[idx];
}

// ---------- fused per-dst gather ----------
#define GT 512
__global__ __launch_bounds__(GT) void gather_agg(
    const unsigned* __restrict__ kv, const float* __restrict__ q,
    const int* __restrict__ csr_src, const int* __restrict__ offs,
    const float* __restrict__ rel_att, const float* __restrict__ rel_msg,
    const float* __restrict__ rel_pri, float* __restrict__ t)
{
    __shared__ float As[32 * MAT_STRIDE];
    __shared__ float Ms[32 * MAT_STRIDE];
    const int tid = threadIdx.x;
    for (int i = tid; i < 32 * MAT_STRIDE; i += GT) {
        int m = i / MAT_STRIDE, off = i % MAT_STRIDE;
        if (off < 256) {
            As[i] = rel_att[m * 256 + off];
            Ms[i] = rel_msg[m * 256 + off];
        }
    }
    __syncthreads();

    int gidx = blockIdx.x * GT + tid;
    if (gidx >= NN * HH) return;
    const int dst = gidx >> 3, h = gidx & 7;

    float qh[16];
    {
        const float4* qp = (const float4*)(q + (long)dst * DD + h * DK);
        #pragma unroll
        for (int i = 0; i < 4; ++i) {
            float4 a = qp[i];
            qh[4*i] = a.x; qh[4*i+1] = a.y; qh[4*i+2] = a.z; qh[4*i+3] = a.w;
        }
    }

    float tacc[16];
    #pragma unroll
    for (int f = 0; f < 16; ++f) tacc[f] = 0.f;

    for (int r = 0; r < RR; ++r) {
        const int seg = r * NN + dst;
        const int beg = offs[seg];
        const int end = (seg == NSEG - 1) ? NEDGE : offs[seg + 1];
        if (end <= beg) continue;                 // empty mailbox contributes 0

        const float* A = &As[(r * HH + h) * MAT_STRIDE];
        const float* M = &Ms[(r * HH + h) * MAT_STRIDE];
        const float pri = rel_pri[r * HH + h] * 0.25f;   // pri / sqrt(dk)

        float qbar[16];
        #pragma unroll
        for (int d = 0; d < 16; ++d) {
            float4 a0 = *(const float4*)(A + d * 16);
            float4 a1 = *(const float4*)(A + d * 16 + 4);
            float4 a2 = *(const float4*)(A + d * 16 + 8);
            float4 a3 = *(const float4*)(A + d * 16 + 12);
            float acc = a0.x * qh[0];
            acc = __builtin_fmaf(a0.y, qh[1], acc);
            acc = __builtin_fmaf(a0.z, qh[2], acc);
            acc = __builtin_fmaf(a0.w, qh[3], acc);
            acc = __builtin_fmaf(a1.x, qh[4], acc);
            acc = __builtin_fmaf(a1.y, qh[5], acc);
            acc = __builtin_fmaf(a1.z, qh[6], acc);
            acc = __builtin_fmaf(a1.w, qh[7], acc);
            acc = __builtin_fmaf(a2.x, qh[8], acc);
            acc = __builtin_fmaf(a2.y, qh[9], acc);
            acc = __builtin_fmaf(a2.z, qh[10], acc);
            acc = __builtin_fmaf(a2.w, qh[11], acc);
            acc = __builtin_fmaf(a3.x, qh[12], acc);
            acc = __builtin_fmaf(a3.y, qh[13], acc);
            acc = __builtin_fmaf(a3.z, qh[14], acc);
            acc = __builtin_fmaf(a3.w, qh[15], acc);
            qbar[d] = acc * pri;                  // fold pri/sqrt(dk) into qbar
        }

        float mx = -INFINITY, s = 0.f;
        float vb[16];
        #pragma unroll
        for (int f = 0; f < 16; ++f) vb[f] = 0.f;

        for (int e = beg; e < end; ++e) {
            int src = csr_src[e];
            const uint4* kvp = (const uint4*)kv + ((long)src * 32 + h * 4);
            uint4 ka = kvp[0], kb = kvp[1];
            uint4 va = kvp[2], vc = kvp[3];

            float att;
            att  = bflo(ka.x) * qbar[0];
            att = __builtin_fmaf(bfhi(ka.x), qbar[1], att);
            att = __builtin_fmaf(bflo(ka.y), qbar[2], att);
            att = __builtin_fmaf(bfhi(ka.y), qbar[3], att);
            att = __builtin_fmaf(bflo(ka.z), qbar[4], att);
            att = __builtin_fmaf(bfhi(ka.z), qbar[5], att);
            att = __builtin_fmaf(bflo(ka.w), qbar[6], att);
            att = __builtin_fmaf(bfhi(ka.w), qbar[7], att);
            att = __builtin_fmaf(bflo(kb.x), qbar[8], att);
            att = __builtin_fmaf(bfhi(kb.x), qbar[9], att);
            att = __builtin_fmaf(bflo(kb.y), qbar[10], att);
            att = __builtin_fmaf(bfhi(kb.y), qbar[11], att);
            att = __builtin_fmaf(bflo(kb.z), qbar[12], att);
            att = __builtin_fmaf(bfhi(kb.z), qbar[13], att);
            att = __builtin_fmaf(bflo(kb.w), qbar[14], att);
            att = __builtin_fmaf(bfhi(kb.w), qbar[15], att);

            float nm = fmaxf(mx, att);
            float eo = __expf(mx - nm);      // 0 on first iteration
            float ea = __expf(att - nm);
            s = s * eo + ea;
            vb[0]  = __builtin_fmaf(vb[0],  eo, ea * bflo(va.x));
            vb[1]  = __builtin_fmaf(vb[1],  eo, ea * bfhi(va.x));
            vb[2]  = __builtin_fmaf(vb[2],  eo, ea * bflo(va.y));
            vb[3]  = __builtin_fmaf(vb[3],  eo, ea * bfhi(va.y));
            vb[4]  = __builtin_fmaf(vb[4],  eo, ea * bflo(va.z));
            vb[5]  = __builtin_fmaf(vb[5],  eo, ea * bfhi(va.z));
            vb[6]  = __builtin_fmaf(vb[6],  eo, ea * bflo(va.w));
            vb[7]  = __builtin_fmaf(vb[7],  eo, ea * bfhi(va.w));
            vb[8]  = __builtin_fmaf(vb[8],  eo, ea * bflo(vc.x));
            vb[9]  = __builtin_fmaf(vb[9],  eo, ea * bfhi(vc.x));
            vb[10] = __builtin_fmaf(vb[10], eo, ea * bflo(vc.y));
            vb[11] = __builtin_fmaf(vb[11], eo, ea * bfhi(vc.y));
            vb[12] = __builtin_fmaf(vb[12], eo, ea * bflo(vc.z));
            vb[13] = __builtin_fmaf(vb[13], eo, ea * bfhi(vc.z));
            vb[14] = __builtin_fmaf(vb[14], eo, ea * bflo(vc.w));
            vb[15] = __builtin_fmaf(vb[15], eo, ea * bfhi(vc.w));
            mx = nm;
        }

        float inv = 1.f / s;
        float u[16];
        #pragma unroll
        for (int f = 0; f < 16; ++f) u[f] = 0.f;
        #pragma unroll
        for (int d = 0; d < 16; ++d) {
            float vd = vb[d];
            float4 m0 = *(const float4*)(M + d * 16);
            float4 m1 = *(const float4*)(M + d * 16 + 4);
            float4 m2 = *(const float4*)(M + d * 16 + 8);
            float4 m3 = *(const float4*)(M + d * 16 + 12);
            u[0]  = __builtin_fmaf(vd, m0.x, u[0]);
            u[1]  = __builtin_fmaf(vd, m0.y, u[1]);
            u[2]  = __builtin_fmaf(vd, m0.z, u[2]);
            u[3]  = __builtin_fmaf(vd, m0.w, u[3]);
            u[4]  = __builtin_fmaf(vd, m1.x, u[4]);
            u[5]  = __builtin_fmaf(vd, m1.y, u[5]);
            u[6]  = __builtin_fmaf(vd, m1.z, u[6]);
            u[7]  = __builtin_fmaf(vd, m1.w, u[7]);
            u[8]  = __builtin_fmaf(vd, m2.x, u[8]);
            u[9]  = __builtin_fmaf(vd, m2.y, u[9]);
            u[10] = __builtin_fmaf(vd, m2.z, u[10]);
            u[11] = __builtin_fmaf(vd, m2.w, u[11]);
            u[12] = __builtin_fmaf(vd, m3.x, u[12]);
            u[13] = __builtin_fmaf(vd, m3.y, u[13]);
            u[14] = __builtin_fmaf(vd, m3.z, u[14]);
            u[15] = __builtin_fmaf(vd, m3.w, u[15]);
        }
        #pragma unroll
        for (int f = 0; f < 16; ++f)
            tacc[f] = __builtin_fmaf(u[f], inv, tacc[f]);
    }

    float* tp = t + (long)dst * DD + h * DK;
    #pragma unroll
    for (int i = 0; i < 4; ++i) {
        float4 o;
        o.x = tacc[4*i]; o.y = tacc[4*i+1]; o.z = tacc[4*i+2]; o.w = tacc[4*i+3];
        *(float4*)(tp + 4 * i) = o;
    }
}

extern "C" void kernel_launch(void* const* d_in, const int* in_sizes, int n_in,
                              void* d_out, int out_size, void* d_ws, size_t ws_size,
                              hipStream_t stream)
{
    const float* x   = (const float*)d_in[0];
    const int* esrc  = (const int*)d_in[1];
    const int* edst  = (const int*)d_in[2];
    const float* Wk  = (const float*)d_in[3];
    const float* bk  = (const float*)d_in[4];
    const float* Wq  = (const float*)d_in[5];
    const float* bq  = (const float*)d_in[6];
    const float* Wv  = (const float*)d_in[7];
    const float* bv  = (const float*)d_in[8];
    const float* Wa  = (const float*)d_in[9];
    const float* ba  = (const float*)d_in[10];
    const float* rel_att = (const float*)d_in[11];
    const float* rel_msg = (const float*)d_in[12];
    const float* rel_pri = (const float*)d_in[13];
    const float* skip    = (const float*)d_in[14];
    float* out = (float*)d_out;

    // ws: [q:ND][t:ND][kv:ND uints] [cnt:NSEG][offs:NSEG][cur:NSEG][bsum:512][csr:NEDGE]
    float* ws = (float*)d_ws;
    const long ND = (long)NN * DD;
    float* qbuf = ws;
    float* tbuf = ws + ND;
    unsigned* kvb = (unsigned*)(ws + 2 * ND);
    int* cnt  = (int*)(ws + 3 * ND);
    int* offs = cnt + NSEG;
    int* cur  = offs + NSEG;
    int* bsum = cur + NSEG;
    int* csr  = bsum + 512;

    hipMemsetAsync(cnt, 0, NSEG * sizeof(int), stream);

    const int gb = (NN + MT - 1) / MT;   // 1563
    gemm_qkv<<<dim3(gb, 3), 256, 0, stream>>>(x, Wq, Wk, Wv, bq, bk, bv, qbuf, kvb);

    const int ebk = (NEDGE + 255) / 256;
    csr_hist<<<ebk, 256, 0, stream>>>(edst, cnt);
    scan1<<<SCAN_NB, SCAN_BLK, 0, stream>>>(cnt, offs, bsum);
    scan2<<<1, 512, 0, stream>>>(bsum);
    scan3<<<SCAN_NB, SCAN_BLK, 0, stream>>>(offs, cur, bsum);
    csr_fill<<<ebk, 256, 0, stream>>>(esrc, edst, cur, csr);

    gather_agg<<<(NN * HH + GT - 1) / GT, GT, 0, stream>>>(
        kvb, qbuf, csr, offs, rel_att, rel_msg, rel_pri, tbuf);

    gemm_out<<<gb, 256, 0, stream>>>(tbuf, Wa, ba, out, 0.25f, skip, x);
}

// Round 6
// 361.407 us; speedup vs baseline: 50.2164x; 1.3969x over previous
//
#include <hip/hip_runtime.h>

#define NN 100000
#define DD 128
#define RR 4
#define EE 150000
#define HH 8
#define DK 16

#define NSEG (RR * NN)        // 400000
#define NEDGE (RR * EE)       // 600000
#define SCAN_BLK 256
#define SCAN_ELEMS 1024
#define SCAN_NB ((NSEG + SCAN_ELEMS - 1) / SCAN_ELEMS)   // 391
#define MAT_STRIDE 264        // 256+8 pad for 16x16 rel matrices in LDS
#define PAD_K 136             // bf16 row stride (272 B): frag reads spread banks

typedef short bf16x8 __attribute__((ext_vector_type(8)));
typedef float f32x4  __attribute__((ext_vector_type(4)));

// f32 -> bf16 round-to-nearest-even (bit pattern as ushort)
__device__ __forceinline__ unsigned short f2bf(float f) {
    unsigned u = __float_as_uint(f);
    return (unsigned short)((u + 0x7fffu + ((u >> 16) & 1u)) >> 16);
}
__device__ __forceinline__ float bflo(unsigned w) { return __uint_as_float(w << 16); }
__device__ __forceinline__ float bfhi(unsigned w) { return __uint_as_float(w & 0xffff0000u); }

// ---------- MFMA bf16 k/q/v projection (grid.y = matrix) ----------
// Tile: 64 X-rows x 128 out-cols. X,W staged once as bf16 in LDS (1 barrier,
// no LDS reuse). 4 waves in 2x2: wave = (wr: 32 X-rows, wc: 64 W-rows).
// mat 0: D = X * Wq^T -> q f32.  mat 1/2: D = W * X^T (swapped operands) so
// each lane holds 4 consecutive d-dims -> pack bf16 pairs in-lane into kv:
// kv[node][h] = 16 bf16 k | 16 bf16 v (64 B line, matches gather layout).
__global__ __launch_bounds__(256) void mfma_qkv(
    const float* __restrict__ X,
    const float* __restrict__ Wq, const float* __restrict__ Wk, const float* __restrict__ Wv,
    const float* __restrict__ bq, const float* __restrict__ bk, const float* __restrict__ bv,
    float* __restrict__ qout, unsigned* __restrict__ kv)
{
    const int tid = threadIdx.x;
    const int lane = tid & 63;
    const int wave = tid >> 6;
    const int wr = wave >> 1;            // X-row half (32 rows)
    const int wc = wave & 1;             // W-row half (64 rows)
    const long m0 = (long)blockIdx.x * 64;
    const int mat = blockIdx.y;
    const float* W    = (mat == 0) ? Wq : (mat == 1) ? Wk : Wv;
    const float* bias = (mat == 0) ? bq : (mat == 1) ? bk : bv;

    __shared__ short Xs[64 * PAD_K];
    __shared__ short Wsh[128 * PAD_K];

    // stage X tile 64x128 f32 -> bf16 (zero-fill OOB rows)
    #pragma unroll
    for (int i = 0; i < 8; ++i) {
        int f = tid + 256 * i;           // float4 slot in 64x32
        int row = f >> 5, c4 = f & 31;
        long m = m0 + row;
        float4 v = make_float4(0.f, 0.f, 0.f, 0.f);
        if (m < NN) v = ((const float4*)(X + m * DD))[c4];
        unsigned u0 = (unsigned)f2bf(v.x) | ((unsigned)f2bf(v.y) << 16);
        unsigned u1 = (unsigned)f2bf(v.z) | ((unsigned)f2bf(v.w) << 16);
        *(uint2*)&Xs[row * PAD_K + c4 * 4] = make_uint2(u0, u1);
    }
    // stage W 128x128 f32 -> bf16
    #pragma unroll
    for (int i = 0; i < 16; ++i) {
        int f = tid + 256 * i;
        int row = f >> 5, c4 = f & 31;
        float4 v = ((const float4*)(W + row * DD))[c4];
        unsigned u0 = (unsigned)f2bf(v.x) | ((unsigned)f2bf(v.y) << 16);
        unsigned u1 = (unsigned)f2bf(v.z) | ((unsigned)f2bf(v.w) << 16);
        *(uint2*)&Wsh[row * PAD_K + c4 * 4] = make_uint2(u0, u1);
    }
    __syncthreads();

    const int lrow = lane & 15;
    const int kg = lane >> 4;            // 0..3

    f32x4 acc[2][4];
    #pragma unroll
    for (int i = 0; i < 2; ++i)
        #pragma unroll
        for (int j = 0; j < 4; ++j) acc[i][j] = (f32x4){0.f, 0.f, 0.f, 0.f};

    #pragma unroll
    for (int ks = 0; ks < 4; ++ks) {
        const int kk = ks * 32 + kg * 8;
        bf16x8 xf[2], wf[4];
        #pragma unroll
        for (int i = 0; i < 2; ++i)
            xf[i] = *(const bf16x8*)&Xs[(wr * 32 + i * 16 + lrow) * PAD_K + kk];
        #pragma unroll
        for (int j = 0; j < 4; ++j)
            wf[j] = *(const bf16x8*)&Wsh[(wc * 64 + j * 16 + lrow) * PAD_K + kk];
        if (mat == 0) {
            #pragma unroll
            for (int i = 0; i < 2; ++i)
                #pragma unroll
                for (int j = 0; j < 4; ++j)
                    acc[i][j] = __builtin_amdgcn_mfma_f32_16x16x32_bf16(xf[i], wf[j], acc[i][j], 0, 0, 0);
        } else {
            #pragma unroll
            for (int i = 0; i < 2; ++i)
                #pragma unroll
                for (int j = 0; j < 4; ++j)
                    acc[i][j] = __builtin_amdgcn_mfma_f32_16x16x32_bf16(wf[j], xf[i], acc[i][j], 0, 0, 0);
        }
    }

    if (mat == 0) {
        // D rows = X rows, D cols = W rows(n). lane: col = lrow, row = kg*4+r
        #pragma unroll
        for (int j = 0; j < 4; ++j) {
            const int n = wc * 64 + j * 16 + lrow;
            const float bcol = bias[n];
            #pragma unroll
            for (int i = 0; i < 2; ++i) {
                #pragma unroll
                for (int r = 0; r < 4; ++r) {
                    long m = m0 + wr * 32 + i * 16 + kg * 4 + r;
                    if (m < NN) qout[m * DD + n] = acc[i][j][r] + bcol;
                }
            }
        }
    } else {
        // swapped: D rows = n (4 consecutive per lane), D cols = X rows m
        const unsigned slotu = (mat == 1) ? 0u : 8u;   // k at +0 uints, v at +8
        #pragma unroll
        for (int j = 0; j < 4; ++j) {
            const int nb = wc * 64 + j * 16 + kg * 4;  // d-base, 4 consecutive
            const float b0 = bias[nb + 0], b1 = bias[nb + 1];
            const float b2 = bias[nb + 2], b3 = bias[nb + 3];
            const int h = nb >> 4, d0 = nb & 15;
            #pragma unroll
            for (int i = 0; i < 2; ++i) {
                long m = m0 + wr * 32 + i * 16 + lrow;
                if (m < NN) {
                    unsigned u0 = (unsigned)f2bf(acc[i][j][0] + b0) | ((unsigned)f2bf(acc[i][j][1] + b1) << 16);
                    unsigned u1 = (unsigned)f2bf(acc[i][j][2] + b2) | ((unsigned)f2bf(acc[i][j][3] + b3) << 16);
                    *(uint2*)&kv[m * 128 + h * 16 + slotu + (d0 >> 1)] = make_uint2(u0, u1);
                }
            }
        }
    }
}

// ---------- MFMA bf16 output GEMM: out = (t/4)@Wa^T + ba, skip-gated ----------
__global__ __launch_bounds__(256) void mfma_out(
    const float* __restrict__ T, const float* __restrict__ Wa, const float* __restrict__ ba,
    float* __restrict__ out, const float* __restrict__ skip, const float* __restrict__ xres)
{
    const int tid = threadIdx.x;
    const int lane = tid & 63;
    const int wave = tid >> 6;
    const int wr = wave >> 1;
    const int wc = wave & 1;
    const long m0 = (long)blockIdx.x * 64;

    __shared__ short Xs[64 * PAD_K];
    __shared__ short Wsh[128 * PAD_K];

    #pragma unroll
    for (int i = 0; i < 8; ++i) {
        int f = tid + 256 * i;
        int row = f >> 5, c4 = f & 31;
        long m = m0 + row;
        float4 v = make_float4(0.f, 0.f, 0.f, 0.f);
        if (m < NN) v = ((const float4*)(T + m * DD))[c4];
        // fold cross-relation mean (1/4, exact in bf16) into the conversion
        unsigned u0 = (unsigned)f2bf(v.x * 0.25f) | ((unsigned)f2bf(v.y * 0.25f) << 16);
        unsigned u1 = (unsigned)f2bf(v.z * 0.25f) | ((unsigned)f2bf(v.w * 0.25f) << 16);
        *(uint2*)&Xs[row * PAD_K + c4 * 4] = make_uint2(u0, u1);
    }
    #pragma unroll
    for (int i = 0; i < 16; ++i) {
        int f = tid + 256 * i;
        int row = f >> 5, c4 = f & 31;
        float4 v = ((const float4*)(Wa + row * DD))[c4];
        unsigned u0 = (unsigned)f2bf(v.x) | ((unsigned)f2bf(v.y) << 16);
        unsigned u1 = (unsigned)f2bf(v.z) | ((unsigned)f2bf(v.w) << 16);
        *(uint2*)&Wsh[row * PAD_K + c4 * 4] = make_uint2(u0, u1);
    }
    __syncthreads();

    const int lrow = lane & 15;
    const int kg = lane >> 4;

    f32x4 acc[2][4];
    #pragma unroll
    for (int i = 0; i < 2; ++i)
        #pragma unroll
        for (int j = 0; j < 4; ++j) acc[i][j] = (f32x4){0.f, 0.f, 0.f, 0.f};

    #pragma unroll
    for (int ks = 0; ks < 4; ++ks) {
        const int kk = ks * 32 + kg * 8;
        bf16x8 xf[2], wf[4];
        #pragma unroll
        for (int i = 0; i < 2; ++i)
            xf[i] = *(const bf16x8*)&Xs[(wr * 32 + i * 16 + lrow) * PAD_K + kk];
        #pragma unroll
        for (int j = 0; j < 4; ++j)
            wf[j] = *(const bf16x8*)&Wsh[(wc * 64 + j * 16 + lrow) * PAD_K + kk];
        #pragma unroll
        for (int i = 0; i < 2; ++i)
            #pragma unroll
            for (int j = 0; j < 4; ++j)
                acc[i][j] = __builtin_amdgcn_mfma_f32_16x16x32_bf16(xf[i], wf[j], acc[i][j], 0, 0, 0);
    }

    const float s = 1.f / (1.f + __expf(-skip[0]));
    const float al = s, bt = 1.f - s;

    #pragma unroll
    for (int j = 0; j < 4; ++j) {
        const int n = wc * 64 + j * 16 + lrow;
        const float bcol = ba[n];
        #pragma unroll
        for (int i = 0; i < 2; ++i) {
            #pragma unroll
            for (int r = 0; r < 4; ++r) {
                long m = m0 + wr * 32 + i * 16 + kg * 4 + r;
                if (m < NN) {
                    long o = m * DD + n;
                    out[o] = __builtin_fmaf(xres[o], bt, (acc[i][j][r] + bcol) * al);
                }
            }
        }
    }
}

// ---------- CSR build: histogram -> scan -> fill ----------
// offs[] is IMMUTABLE after scan; csr_fill bumps cur[].

__global__ __launch_bounds__(256) void csr_hist(
    const int* __restrict__ edst, int* __restrict__ cnt)
{
    int idx = blockIdx.x * 256 + threadIdx.x;
    if (idx >= NEDGE) return;
    int r = idx / EE;
    atomicAdd(&cnt[r * NN + edst[idx]], 1);
}

__global__ __launch_bounds__(SCAN_BLK) void scan1(
    const int* __restrict__ cnt, int* __restrict__ offs, int* __restrict__ bsum)
{
    __shared__ int sh[SCAN_BLK];
    int blk = blockIdx.x, tid = threadIdx.x;
    int base = blk * SCAN_ELEMS + tid * 4;
    int v0 = 0, v1 = 0, v2 = 0, v3 = 0;
    if (base + 3 < NSEG) {
        int4 t = *(const int4*)(cnt + base);
        v0 = t.x; v1 = t.y; v2 = t.z; v3 = t.w;
    } else {
        if (base + 0 < NSEG) v0 = cnt[base + 0];
        if (base + 1 < NSEG) v1 = cnt[base + 1];
        if (base + 2 < NSEG) v2 = cnt[base + 2];
        if (base + 3 < NSEG) v3 = cnt[base + 3];
    }
    int tsum = v0 + v1 + v2 + v3;
    sh[tid] = tsum;
    __syncthreads();
    #pragma unroll
    for (int d = 1; d < SCAN_BLK; d <<= 1) {
        int x = (tid >= d) ? sh[tid - d] : 0;
        __syncthreads();
        sh[tid] += x;
        __syncthreads();
    }
    int excl = sh[tid] - tsum;
    int r0 = excl, r1 = r0 + v0, r2 = r1 + v1, r3 = r2 + v2;
    if (base + 3 < NSEG) {
        *(int4*)(offs + base) = make_int4(r0, r1, r2, r3);
    } else {
        if (base + 0 < NSEG) offs[base + 0] = r0;
        if (base + 1 < NSEG) offs[base + 1] = r1;
        if (base + 2 < NSEG) offs[base + 2] = r2;
        if (base + 3 < NSEG) offs[base + 3] = r3;
    }
    if (tid == SCAN_BLK - 1) bsum[blk] = sh[tid];
}

__global__ __launch_bounds__(512) void scan2(int* __restrict__ bsum)
{
    __shared__ int sh[512];
    int tid = threadIdx.x;
    int v = (tid < SCAN_NB) ? bsum[tid] : 0;
    sh[tid] = v;
    __syncthreads();
    #pragma unroll
    for (int d = 1; d < 512; d <<= 1) {
        int x = (tid >= d) ? sh[tid - d] : 0;
        __syncthreads();
        sh[tid] += x;
        __syncthreads();
    }
    if (tid < SCAN_NB) bsum[tid] = sh[tid] - v;   // exclusive block sums
}

__global__ __launch_bounds__(SCAN_BLK) void scan3(
    int* __restrict__ offs, int* __restrict__ cur, const int* __restrict__ bsum)
{
    int blk = blockIdx.x;
    int add = bsum[blk];
    int base = blk * SCAN_ELEMS + threadIdx.x * 4;
    #pragma unroll
    for (int j = 0; j < 4; ++j)
        if (base + j < NSEG) {
            int v = offs[base + j] + add;
            offs[base + j] = v;
            cur[base + j] = v;
        }
}

__global__ __launch_bounds__(256) void csr_fill(
    const int* __restrict__ esrc, const int* __restrict__ edst,
    int* __restrict__ cur, int* __restrict__ csr_src)
{
    int idx = blockIdx.x * 256 + threadIdx.x;
    if (idx >= NEDGE) return;
    int r = idx / EE;
    int pos = atomicAdd(&cur[r * NN + edst[idx]], 1);
    csr_src[pos] = esrc[idx];
}

// ---------- fused per-dst gather ----------
#define GT 512
__global__ __launch_bounds__(GT) void gather_agg(
    const unsigned* __restrict__ kv, const float* __restrict__ q,
    const int* __restrict__ csr_src, const int* __restrict__ offs,
    const float* __restrict__ rel_att, const float* __restrict__ rel_msg,
    const float* __restrict__ rel_pri, float* __restrict__ t)
{
    __shared__ float As[32 * MAT_STRIDE];
    __shared__ float Ms[32 * MAT_STRIDE];
    const int tid = threadIdx.x;
    for (int i = tid; i < 32 * MAT_STRIDE; i += GT) {
        int m = i / MAT_STRIDE, off = i % MAT_STRIDE;
        if (off < 256) {
            As[i] = rel_att[m * 256 + off];
            Ms[i] = rel_msg[m * 256 + off];
        }
    }
    __syncthreads();

    int gidx = blockIdx.x * GT + tid;
    if (gidx >= NN * HH) return;
    const int dst = gidx >> 3, h = gidx & 7;

    float qh[16];
    {
        const float4* qp = (const float4*)(q + (long)dst * DD + h * DK);
        #pragma unroll
        for (int i = 0; i < 4; ++i) {
            float4 a = qp[i];
            qh[4*i] = a.x; qh[4*i+1] = a.y; qh[4*i+2] = a.z; qh[4*i+3] = a.w;
        }
    }

    float tacc[16];
    #pragma unroll
    for (int f = 0; f < 16; ++f) tacc[f] = 0.f;

    for (int r = 0; r < RR; ++r) {
        const int seg = r * NN + dst;
        const int beg = offs[seg];
        const int end = (seg == NSEG - 1) ? NEDGE : offs[seg + 1];
        if (end <= beg) continue;                 // empty mailbox contributes 0

        const float* A = &As[(r * HH + h) * MAT_STRIDE];
        const float* M = &Ms[(r * HH + h) * MAT_STRIDE];
        const float pri = rel_pri[r * HH + h] * 0.25f;   // pri / sqrt(dk)

        float qbar[16];
        #pragma unroll
        for (int d = 0; d < 16; ++d) {
            float4 a0 = *(const float4*)(A + d * 16);
            float4 a1 = *(const float4*)(A + d * 16 + 4);
            float4 a2 = *(const float4*)(A + d * 16 + 8);
            float4 a3 = *(const float4*)(A + d * 16 + 12);
            float acc = a0.x * qh[0];
            acc = __builtin_fmaf(a0.y, qh[1], acc);
            acc = __builtin_fmaf(a0.z, qh[2], acc);
            acc = __builtin_fmaf(a0.w, qh[3], acc);
            acc = __builtin_fmaf(a1.x, qh[4], acc);
            acc = __builtin_fmaf(a1.y, qh[5], acc);
            acc = __builtin_fmaf(a1.z, qh[6], acc);
            acc = __builtin_fmaf(a1.w, qh[7], acc);
            acc = __builtin_fmaf(a2.x, qh[8], acc);
            acc = __builtin_fmaf(a2.y, qh[9], acc);
            acc = __builtin_fmaf(a2.z, qh[10], acc);
            acc = __builtin_fmaf(a2.w, qh[11], acc);
            acc = __builtin_fmaf(a3.x, qh[12], acc);
            acc = __builtin_fmaf(a3.y, qh[13], acc);
            acc = __builtin_fmaf(a3.z, qh[14], acc);
            acc = __builtin_fmaf(a3.w, qh[15], acc);
            qbar[d] = acc * pri;                  // fold pri/sqrt(dk) into qbar
        }

        float mx = -INFINITY, s = 0.f;
        float vb[16];
        #pragma unroll
        for (int f = 0; f < 16; ++f) vb[f] = 0.f;

        for (int e = beg; e < end; ++e) {
            int src = csr_src[e];
            const uint4* kvp = (const uint4*)kv + ((long)src * 32 + h * 4);
            uint4 ka = kvp[0], kb = kvp[1];
            uint4 va = kvp[2], vc = kvp[3];

            float att;
            att  = bflo(ka.x) * qbar[0];
            att = __builtin_fmaf(bfhi(ka.x), qbar[1], att);
            att = __builtin_fmaf(bflo(ka.y), qbar[2], att);
            att = __builtin_fmaf(bfhi(ka.y), qbar[3], att);
            att = __builtin_fmaf(bflo(ka.z), qbar[4], att);
            att = __builtin_fmaf(bfhi(ka.z), qbar[5], att);
            att = __builtin_fmaf(bflo(ka.w), qbar[6], att);
            att = __builtin_fmaf(bfhi(ka.w), qbar[7], att);
            att = __builtin_fmaf(bflo(kb.x), qbar[8], att);
            att = __builtin_fmaf(bfhi(kb.x), qbar[9], att);
            att = __builtin_fmaf(bflo(kb.y), qbar[10], att);
            att = __builtin_fmaf(bfhi(kb.y), qbar[11], att);
            att = __builtin_fmaf(bflo(kb.z), qbar[12], att);
            att = __builtin_fmaf(bfhi(kb.z), qbar[13], att);
            att = __builtin_fmaf(bflo(kb.w), qbar[14], att);
            att = __builtin_fmaf(bfhi(kb.w), qbar[15], att);

            float nm = fmaxf(mx, att);
            float eo = __expf(mx - nm);      // 0 on first iteration
            float ea = __expf(att - nm);
            s = s * eo + ea;
            vb[0]  = __builtin_fmaf(vb[0],  eo, ea * bflo(va.x));
            vb[1]  = __builtin_fmaf(vb[1],  eo, ea * bfhi(va.x));
            vb[2]  = __builtin_fmaf(vb[2],  eo, ea * bflo(va.y));
            vb[3]  = __builtin_fmaf(vb[3],  eo, ea * bfhi(va.y));
            vb[4]  = __builtin_fmaf(vb[4],  eo, ea * bflo(va.z));
            vb[5]  = __builtin_fmaf(vb[5],  eo, ea * bfhi(va.z));
            vb[6]  = __builtin_fmaf(vb[6],  eo, ea * bflo(va.w));
            vb[7]  = __builtin_fmaf(vb[7],  eo, ea * bfhi(va.w));
            vb[8]  = __builtin_fmaf(vb[8],  eo, ea * bflo(vc.x));
            vb[9]  = __builtin_fmaf(vb[9],  eo, ea * bfhi(vc.x));
            vb[10] = __builtin_fmaf(vb[10], eo, ea * bflo(vc.y));
            vb[11] = __builtin_fmaf(vb[11], eo, ea * bfhi(vc.y));
            vb[12] = __builtin_fmaf(vb[12], eo, ea * bflo(vc.z));
            vb[13] = __builtin_fmaf(vb[13], eo, ea * bfhi(vc.z));
            vb[14] = __builtin_fmaf(vb[14], eo, ea * bflo(vc.w));
            vb[15] = __builtin_fmaf(vb[15], eo, ea * bfhi(vc.w));
            mx = nm;
        }

        float inv = 1.f / s;
        float u[16];
        #pragma unroll
        for (int f = 0; f < 16; ++f) u[f] = 0.f;
        #pragma unroll
        for (int d = 0; d < 16; ++d) {
            float vd = vb[d];
            float4 m0 = *(const float4*)(M + d * 16);
            float4 m1 = *(const float4*)(M + d * 16 + 4);
            float4 m2 = *(const float4*)(M + d * 16 + 8);
            float4 m3 = *(const float4*)(M + d * 16 + 12);
            u[0]  = __builtin_fmaf(vd, m0.x, u[0]);
            u[1]  = __builtin_fmaf(vd, m0.y, u[1]);
            u[2]  = __builtin_fmaf(vd, m0.z, u[2]);
            u[3]  = __builtin_fmaf(vd, m0.w, u[3]);
            u[4]  = __builtin_fmaf(vd, m1.x, u[4]);
            u[5]  = __builtin_fmaf(vd, m1.y, u[5]);
            u[6]  = __builtin_fmaf(vd, m1.z, u[6]);
            u[7]  = __builtin_fmaf(vd, m1.w, u[7]);
            u[8]  = __builtin_fmaf(vd, m2.x, u[8]);
            u[9]  = __builtin_fmaf(vd, m2.y, u[9]);
            u[10] = __builtin_fmaf(vd, m2.z, u[10]);
            u[11] = __builtin_fmaf(vd, m2.w, u[11]);
            u[12] = __builtin_fmaf(vd, m3.x, u[12]);
            u[13] = __builtin_fmaf(vd, m3.y, u[13]);
            u[14] = __builtin_fmaf(vd, m3.z, u[14]);
            u[15] = __builtin_fmaf(vd, m3.w, u[15]);
        }
        #pragma unroll
        for (int f = 0; f < 16; ++f)
            tacc[f] = __builtin_fmaf(u[f], inv, tacc[f]);
    }

    float* tp = t + (long)dst * DD + h * DK;
    #pragma unroll
    for (int i = 0; i < 4; ++i) {
        float4 o;
        o.x = tacc[4*i]; o.y = tacc[4*i+1]; o.z = tacc[4*i+2]; o.w = tacc[4*i+3];
        *(float4*)(tp + 4 * i) = o;
    }
}

extern "C" void kernel_launch(void* const* d_in, const int* in_sizes, int n_in,
                              void* d_out, int out_size, void* d_ws, size_t ws_size,
                              hipStream_t stream)
{
    const float* x   = (const float*)d_in[0];
    const int* esrc  = (const int*)d_in[1];
    const int* edst  = (const int*)d_in[2];
    const float* Wk  = (const float*)d_in[3];
    const float* bk  = (const float*)d_in[4];
    const float* Wq  = (const float*)d_in[5];
    const float* bq  = (const float*)d_in[6];
    const float* Wv  = (const float*)d_in[7];
    const float* bv  = (const float*)d_in[8];
    const float* Wa  = (const float*)d_in[9];
    const float* ba  = (const float*)d_in[10];
    const float* rel_att = (const float*)d_in[11];
    const float* rel_msg = (const float*)d_in[12];
    const float* rel_pri = (const float*)d_in[13];
    const float* skip    = (const float*)d_in[14];
    float* out = (float*)d_out;

    // ws: [q:ND][t:ND][kv:ND uints] [cnt:NSEG][offs:NSEG][cur:NSEG][bsum:512][csr:NEDGE]
    float* ws = (float*)d_ws;
    const long ND = (long)NN * DD;
    float* qbuf = ws;
    float* tbuf = ws + ND;
    unsigned* kvb = (unsigned*)(ws + 2 * ND);
    int* cnt  = (int*)(ws + 3 * ND);
    int* offs = cnt + NSEG;
    int* cur  = offs + NSEG;
    int* bsum = cur + NSEG;
    int* csr  = bsum + 512;

    hipMemsetAsync(cnt, 0, NSEG * sizeof(int), stream);

    const int gb = (NN + 63) / 64;   // 1563
    mfma_qkv<<<dim3(gb, 3), 256, 0, stream>>>(x, Wq, Wk, Wv, bq, bk, bv, qbuf, kvb);

    const int ebk = (NEDGE + 255) / 256;
    csr_hist<<<ebk, 256, 0, stream>>>(edst, cnt);
    scan1<<<SCAN_NB, SCAN_BLK, 0, stream>>>(cnt, offs, bsum);
    scan2<<<1, 512, 0, stream>>>(bsum);
    scan3<<<SCAN_NB, SCAN_BLK, 0, stream>>>(offs, cur, bsum);
    csr_fill<<<ebk, 256, 0, stream>>>(esrc, edst, cur, csr);

    gather_agg<<<(NN * HH + GT - 1) / GT, GT, 0, stream>>>(
        kvb, qbuf, csr, offs, rel_att, rel_msg, rel_pri, tbuf);

    mfma_out<<<gb, 256, 0, stream>>>(tbuf, Wa, ba, out, skip, x);
}